// Round 5
// baseline (20.470 us; speedup 1.0000x reference)
//
#include <hip/hip_runtime.h>
#include <hip/hip_bf16.h>

// Polyphase resampler, up=2/down=3, 128-tap FIR, via bf16 MFMA.
//   out[2g]   = 2 * sum_m x[31+3g-m] * f[2m+1]
//   out[2g+1] = 2 * sum_m x[33+3g-m] * f[2m]
// W_g[k] = x[3g-32+k]; fe_r[u]=f[127-2u], fo_r[u]=f[126-2u]:
//   out[2g]   = 2 * sum_u W_g[u]   * fe_r[u]
//   out[2g+1] = 2 * sum_u W_g[u+2] * fo_r[u]
// MFMA 16x16x32 bf16, K=96: A[i][k] = x[3(g0+8i)-32+k] (im2col from LDS),
// B[k][2d+ph] = (ph? fo_r : fe_r)[k-3d-2ph]  =>  D[i][j] = out[2g0+16i+j].
//
// R5: GPB 4096->1024 (2731 blocks, ~8 resident/CU: balance + latency TLP);
// B-table precomputed once into d_ws by a 1-block kernel (was 24 divergent
// gathers + ~150 VALU per thread per block).

typedef __bf16 bf16x8 __attribute__((ext_vector_type(8)));
typedef float  f32x4  __attribute__((ext_vector_type(4)));

constexpr int BT  = 256;            // 4 waves
constexpr int GPB = 1024;           // output pairs (g) per block
constexpr int UPW = GPB / 128 / 4;  // 128-pair MFMA units per wave (= 2)
constexpr int XT  = 3 * GPB + 96;   // 3168 staged bf16 x-elements
constexpr int XT4 = XT / 4;         // 792 float4 groups

// ---- one-block pre-kernel: B-fragment table -> d_ws (3KB bf16) ----
__global__ void build_btab(const float* __restrict__ filt,
                           unsigned short* __restrict__ btab)
{
    const int l = threadIdx.x;            // 0..63
    const int j = l & 15, kq = (l >> 4) * 8, dlt = j >> 1, ph = j & 1;
    for (int kc = 0; kc < 3; ++kc) {
        for (int e = 0; e < 8; ++e) {
            int k = 32 * kc + kq + e;
            int v = k - 3 * dlt - 2 * ph;          // tap index u
            float fv = (v >= 0 && v < 64) ? filt[(ph ? 126 : 127) - 2 * v] : 0.0f;
            __hip_bfloat16 b = __float2bfloat16(fv);
            btab[(kc * 64 + l) * 8 + e] = *reinterpret_cast<unsigned short*>(&b);
        }
    }
}

__global__ __launch_bounds__(BT) void resample23_mfma(
    const float* __restrict__ x,
    const unsigned short* __restrict__ btab,
    float* __restrict__ out,
    int N, int out_size)
{
    __shared__ __align__(16) unsigned short xs[XT];   // bf16 x tile (6336 B)

    const int t = threadIdx.x;
    const int w = t >> 6;
    const int l = t & 63;
    const int j = l & 15;
    const int G0 = blockIdx.x * GPB;
    const long F0 = 3L * G0 - 32;       // global float idx of xs[0]

    // ---- B fragments: 3 coalesced bf16x8 loads (L2-broadcast) ----
    const bf16x8* bt = reinterpret_cast<const bf16x8*>(btab);
    bf16x8 Bf0 = bt[0 * 64 + l];
    bf16x8 Bf1 = bt[1 * 64 + l];
    bf16x8 Bf2 = bt[2 * 64 + l];

    // ---- stage x tile: f32 global -> bf16 LDS (coalesced float4) ----
    const bool interior = (F0 >= 0) && (F0 + XT <= (long)N);
    #pragma unroll
    for (int r = 0; r < (XT4 + BT - 1) / BT; ++r) {
        int idx = t + BT * r;
        if (idx < XT4) {
            long f0 = F0 + 4L * idx;
            float4 v;
            if (interior) {
                v = *reinterpret_cast<const float4*>(x + f0);
            } else {
                v.x = (f0 + 0 >= 0 && f0 + 0 < N) ? x[f0 + 0] : 0.0f;
                v.y = (f0 + 1 >= 0 && f0 + 1 < N) ? x[f0 + 1] : 0.0f;
                v.z = (f0 + 2 >= 0 && f0 + 2 < N) ? x[f0 + 2] : 0.0f;
                v.w = (f0 + 3 >= 0 && f0 + 3 < N) ? x[f0 + 3] : 0.0f;
            }
            __hip_bfloat162 p0 = __float22bfloat162_rn(make_float2(v.x, v.y));
            __hip_bfloat162 p1 = __float22bfloat162_rn(make_float2(v.z, v.w));
            *reinterpret_cast<__hip_bfloat162*>(&xs[4 * idx + 0]) = p0;
            *reinterpret_cast<__hip_bfloat162*>(&xs[4 * idx + 2]) = p1;
        }
    }
    __syncthreads();

    // ---- MFMA-triples: 256 contiguous outputs each ----
    const char* xsb = reinterpret_cast<const char*>(xs);
    #pragma unroll
    for (int s = 0; s < UPW; ++s) {
        const int u    = UPW * w + s;                  // 128-pair unit
        const int g0   = G0 + 128 * u;
        const int boff = 768 * u + 48 * j + 16 * (l >> 4);

        f32x4 acc = {0.0f, 0.0f, 0.0f, 0.0f};
        bf16x8 a0 = *reinterpret_cast<const bf16x8*>(xsb + boff + 0);
        bf16x8 a1 = *reinterpret_cast<const bf16x8*>(xsb + boff + 64);
        bf16x8 a2 = *reinterpret_cast<const bf16x8*>(xsb + boff + 128);
        acc = __builtin_amdgcn_mfma_f32_16x16x32_bf16(a0, Bf0, acc, 0, 0, 0);
        acc = __builtin_amdgcn_mfma_f32_16x16x32_bf16(a1, Bf1, acc, 0, 0, 0);
        acc = __builtin_amdgcn_mfma_f32_16x16x32_bf16(a2, Bf2, acc, 0, 0, 0);

        // D[i][j]: col=j, row=4*(l>>4)+r  ->  out[2*g0 + 16*row + col]
        const int obase = 2 * g0 + 64 * (l >> 4) + j;
        #pragma unroll
        for (int r = 0; r < 4; ++r) {
            int o = obase + 16 * r;
            if (o < out_size) out[o] = 2.0f * acc[r];
        }
    }
}

extern "C" void kernel_launch(void* const* d_in, const int* in_sizes, int n_in,
                              void* d_out, int out_size, void* d_ws, size_t ws_size,
                              hipStream_t stream)
{
    const float* x    = (const float*)d_in[0];
    const float* filt = (const float*)d_in[1];
    float* out        = (float*)d_out;
    const int N       = in_sizes[0];
    unsigned short* btab = (unsigned short*)d_ws;

    build_btab<<<1, 64, 0, stream>>>(filt, btab);

    const int n_pairs = (out_size + 1) / 2;
    const int blocks  = (n_pairs + GPB - 1) / GPB;
    resample23_mfma<<<blocks, BT, 0, stream>>>(x, btab, out, N, out_size);
}

// Round 6
// 18.211 us; speedup vs baseline: 1.1241x; 1.1241x over previous
//
#include <hip/hip_runtime.h>
#include <hip/hip_bf16.h>

// Polyphase resampler, up=2/down=3, 128-tap FIR, via bf16 MFMA.
//   out[2g]   = 2 * sum_m x[31+3g-m] * f[2m+1]
//   out[2g+1] = 2 * sum_m x[33+3g-m] * f[2m]
// W_g[k] = x[3g-32+k]; fe_r[u]=f[127-2u], fo_r[u]=f[126-2u]:
//   out[2g]   = 2 * sum_u W_g[u]   * fe_r[u]
//   out[2g+1] = 2 * sum_u W_g[u+2] * fo_r[u]
// MFMA 16x16x32 bf16, K=96: A[i][k] = x[3(g0+8i)-32+k] (im2col from LDS),
// B[k][2d+ph] = (ph? fo_r : fe_r)[k-3d-2ph]  =>  D[i][j] = out[2g0+16i+j].
//
// R6: revert R5's pre-kernel (serialized dispatch cost ~2.5us); back to
// R4's single-kernel inline-B structure. One change vs R4: GPB 4096->2048
// (1366 blocks = 5.33/CU) to cut tail imbalance 12% -> 4%.

typedef __bf16 bf16x8 __attribute__((ext_vector_type(8)));
typedef float  f32x4  __attribute__((ext_vector_type(4)));

constexpr int BT  = 256;            // 4 waves
constexpr int GPB = 2048;           // output pairs (g) per block
constexpr int UPW = GPB / 128 / 4;  // 128-pair MFMA units per wave (= 4)
constexpr int XT  = 3 * GPB + 96;   // 6240 staged bf16 x-elements
constexpr int XT4 = XT / 4;         // 1560 float4 groups

__global__ __launch_bounds__(BT) void resample23_mfma(
    const float* __restrict__ x,
    const float* __restrict__ filt,
    float* __restrict__ out,
    int N, int out_size)
{
    __shared__ __align__(16) unsigned short xs[XT];   // bf16 x tile (12480 B)

    const int t = threadIdx.x;
    const int w = t >> 6;
    const int l = t & 63;
    const int j = l & 15;
    const int G0 = blockIdx.x * GPB;
    const long F0 = 3L * G0 - 32;       // global float idx of xs[0]

    // ---- stage x tile: f32 global -> bf16 LDS (coalesced float4) ----
    const bool interior = (F0 >= 0) && (F0 + XT <= (long)N);
    #pragma unroll
    for (int r = 0; r < (XT4 + BT - 1) / BT; ++r) {
        int idx = t + BT * r;
        if (idx < XT4) {
            long f0 = F0 + 4L * idx;
            float4 v;
            if (interior) {
                v = *reinterpret_cast<const float4*>(x + f0);
            } else {
                v.x = (f0 + 0 >= 0 && f0 + 0 < N) ? x[f0 + 0] : 0.0f;
                v.y = (f0 + 1 >= 0 && f0 + 1 < N) ? x[f0 + 1] : 0.0f;
                v.z = (f0 + 2 >= 0 && f0 + 2 < N) ? x[f0 + 2] : 0.0f;
                v.w = (f0 + 3 >= 0 && f0 + 3 < N) ? x[f0 + 3] : 0.0f;
            }
            __hip_bfloat162 p0 = __float22bfloat162_rn(make_float2(v.x, v.y));
            __hip_bfloat162 p1 = __float22bfloat162_rn(make_float2(v.z, v.w));
            *reinterpret_cast<__hip_bfloat162*>(&xs[4 * idx + 0]) = p0;
            *reinterpret_cast<__hip_bfloat162*>(&xs[4 * idx + 2]) = p1;
        }
    }

    // ---- build B fragments (inline, overlaps staging latency) ----
    const int kq  = (l >> 4) * 8;
    const int dlt = j >> 1;
    const int ph  = j & 1;
    bf16x8 Bf[3];
    #pragma unroll
    for (int kc = 0; kc < 3; ++kc) {
        #pragma unroll
        for (int e = 0; e < 8; ++e) {
            int k = 32 * kc + kq + e;
            int v = k - 3 * dlt - 2 * ph;           // tap index u
            float fv = (v >= 0 && v < 64) ? filt[(ph ? 126 : 127) - 2 * v] : 0.0f;
            Bf[kc][e] = (__bf16)fv;
        }
    }

    __syncthreads();

    // ---- MFMA-triples: 256 contiguous outputs each ----
    const char* xsb = reinterpret_cast<const char*>(xs);
    #pragma unroll
    for (int s = 0; s < UPW; ++s) {
        const int u    = UPW * w + s;                  // 128-pair unit
        const int g0   = G0 + 128 * u;
        const int boff = 768 * u + 48 * j + 16 * (l >> 4);

        f32x4 acc = {0.0f, 0.0f, 0.0f, 0.0f};
        bf16x8 a0 = *reinterpret_cast<const bf16x8*>(xsb + boff + 0);
        bf16x8 a1 = *reinterpret_cast<const bf16x8*>(xsb + boff + 64);
        bf16x8 a2 = *reinterpret_cast<const bf16x8*>(xsb + boff + 128);
        acc = __builtin_amdgcn_mfma_f32_16x16x32_bf16(a0, Bf[0], acc, 0, 0, 0);
        acc = __builtin_amdgcn_mfma_f32_16x16x32_bf16(a1, Bf[1], acc, 0, 0, 0);
        acc = __builtin_amdgcn_mfma_f32_16x16x32_bf16(a2, Bf[2], acc, 0, 0, 0);

        // D[i][j]: col=j, row=4*(l>>4)+r  ->  out[2*g0 + 16*row + col]
        const int obase = 2 * g0 + 64 * (l >> 4) + j;
        #pragma unroll
        for (int r = 0; r < 4; ++r) {
            int o = obase + 16 * r;
            if (o < out_size) out[o] = 2.0f * acc[r];
        }
    }
}

extern "C" void kernel_launch(void* const* d_in, const int* in_sizes, int n_in,
                              void* d_out, int out_size, void* d_ws, size_t ws_size,
                              hipStream_t stream)
{
    const float* x    = (const float*)d_in[0];
    const float* filt = (const float*)d_in[1];
    float* out        = (float*)d_out;
    const int N       = in_sizes[0];

    const int n_pairs = (out_size + 1) / 2;
    const int blocks  = (n_pairs + GPB - 1) / GPB;
    resample23_mfma<<<blocks, BT, 0, stream>>>(x, filt, out, N, out_size);
}